// Round 4
// baseline (645.828 us; speedup 1.0000x reference)
//
#include <hip/hip_runtime.h>

#define CH 256
#define KC 8192
#define NT 32768

#define TM 128         // tokens per block (A persistent in LDS)
#define TN 128         // codes per jt tile (4 waves x 32)
#define BK 32          // channels per stage
#define NSTG ((KC / TN) * (CH / BK))   // 64 jt * 8 cc = 512 stages

typedef _Float16 half4_t __attribute__((ext_vector_type(4)));
typedef _Float16 half8_t __attribute__((ext_vector_type(8)));
typedef float floatx4 __attribute__((ext_vector_type(4)));

typedef __attribute__((address_space(1))) const unsigned int guint_t;
typedef __attribute__((address_space(3))) unsigned int luint_t;

// ---------------------------------------------------------------------------
// Kernel 1 (fused prep):
//  blocks [0, KC):   codebook row -> fp16 hi/lo + cbsq, zero hist
//  blocks [KC, ...): split embeddings fp32 -> fp16 hi/lo (1 float4/thread)
// ---------------------------------------------------------------------------
__global__ void k_prep(const float* __restrict__ usage,
                       const float* __restrict__ ces,
                       const float* __restrict__ emb,
                       _Float16* __restrict__ cbh,
                       _Float16* __restrict__ cbl,
                       float* __restrict__ cbsq,
                       _Float16* __restrict__ eh,
                       _Float16* __restrict__ el,
                       int* __restrict__ hist) {
    int b = blockIdx.x, t = threadIdx.x;
    if (b < KC) {
        float uc = fmaxf(usage[b], 1e-5f);
        float v  = ces[b * CH + t];
        float cb = v / uc;
        _Float16 h = (_Float16)cb;
        cbh[b * CH + t] = h;
        cbl[b * CH + t] = (_Float16)(cb - (float)h);

        float p = cb * cb;
        #pragma unroll
        for (int off = 32; off; off >>= 1) p += __shfl_down(p, off);
        __shared__ float ps[4];
        int lane = t & 63, w = t >> 6;
        if (lane == 0) ps[w] = p;
        __syncthreads();
        if (t == 0) cbsq[b] = ps[0] + ps[1] + ps[2] + ps[3];
        if (t == 1) hist[b] = 0;
    } else {
        int i = (b - KC) * 256 + t;      // float4 index
        float4 v = ((const float4*)emb)[i];
        float va[4] = {v.x, v.y, v.z, v.w};
        half4_t h, l;
        #pragma unroll
        for (int q = 0; q < 4; ++q) {
            _Float16 hh = (_Float16)va[q];
            h[q] = hh;
            l[q] = (_Float16)(va[q] - (float)hh);
        }
        ((half4_t*)eh)[i] = h;
        ((half4_t*)el)[i] = l;
    }
}

// ---------------------------------------------------------------------------
// Kernel 2: fp16-split MFMA argmin — BARRIER-FREE self-timed pipeline.
// 4 waves/block (1/SIMD), wave tile = 128 tokens x 32 codes. A (128 KiB,
// hi+lo) is LDS-persistent after one prologue barrier. Each wave streams its
// OWN private 32-code B strip (4 KiB/stage, double-buffered): no cross-wave
// production -> the 512-stage loop has NO barriers. Per iter: vmcnt(0)+
// lgkmcnt(0) (everything outstanding is >= 1 stage old -> ~free), issue
// DMA(s+2), read fragments F(s+1) (register double-buffer, static indices
// via 2x-unrolled macro), 48 MFMA on F(s). Linear LDS layouts (16 rows x
// 4 chunks per read = dense 1 KiB) are conflict-free; swizzle removed.
// ---------------------------------------------------------------------------
__launch_bounds__(256, 1)
__global__ void k_argmin(const _Float16* __restrict__ eh,
                         const _Float16* __restrict__ el,
                         const _Float16* __restrict__ cbh,
                         const _Float16* __restrict__ cbl,
                         const float* __restrict__ cbsq,
                         unsigned long long* __restrict__ packed) {
    __shared__ __align__(16) unsigned char smraw[163840];
    _Float16* smA = (_Float16*)smraw;     // [hl][cc8][row128][ch32] halves

    const int t    = threadIdx.x;
    const int lane = t & 63;
    const int wave = t >> 6;          // 0..3 = code quarter (32 codes)
    const int wx   = wave;
    const int lr   = lane & 15;
    const int koq  = lane >> 4;       // k-chunk for fragments
    const int lrow4 = lane >> 2;      // DMA: row within 16-row group
    const int ch4   = lane & 3;       // DMA: 16B chunk within row

    const int n0 = blockIdx.x * TM;

    char*      smBw  = (char*)smraw + 131072 + wave * 8192;  // private B dbuf
    _Float16*  smBwh = (_Float16*)smBw;

    float minv[32];
    int   mini[32];
    #pragma unroll
    for (int e = 0; e < 32; ++e) { minv[e] = 3.402823466e38f; mini[e] = 0; }

    floatx4 acc[8][2];
    #pragma unroll
    for (int mf = 0; mf < 8; ++mf) {
        acc[mf][0] = (floatx4){0.f, 0.f, 0.f, 0.f};
        acc[mf][1] = (floatx4){0.f, 0.f, 0.f, 0.f};
    }

    // B stage DMA: this wave's 32 codes, 32 ch, hi+lo = 4 x 1KB issues.
    auto dmaB = [&](int buf, int sg) {
        const int c0 = (sg & 7) * BK;
        const int jb = (sg >> 3) * TN + wx * 32;
        const _Float16* gh = cbh + (size_t)(jb + lrow4) * CH + c0 + ch4 * 8;
        const _Float16* gl = cbl + (size_t)(jb + lrow4) * CH + c0 + ch4 * 8;
        char* d = smBw + buf * 4096;
        __builtin_amdgcn_global_load_lds((guint_t*)gh,
                                         (luint_t*)(d), 16, 0, 0);
        __builtin_amdgcn_global_load_lds((guint_t*)(gh + 16 * CH),
                                         (luint_t*)(d + 1024), 16, 0, 0);
        __builtin_amdgcn_global_load_lds((guint_t*)gl,
                                         (luint_t*)(d + 2048), 16, 0, 0);
        __builtin_amdgcn_global_load_lds((guint_t*)(gl + 16 * CH),
                                         (luint_t*)(d + 3072), 16, 0, 0);
    };

    // ---- prologue: A tile (once, all waves) + B stages 0,1 ----
    {
        const int hl  = wave >> 1;
        const int ccb = (wave & 1) * 4;
        const _Float16* a_hl = hl ? el : eh;
        #pragma unroll
        for (int d = 0; d < 4; ++d) {
            const int cc = ccb + d;
            #pragma unroll
            for (int p = 0; p < 8; ++p) {
                const _Float16* g = a_hl + (size_t)(n0 + p * 16 + lrow4) * CH
                                  + cc * 32 + ch4 * 8;
                __builtin_amdgcn_global_load_lds(
                    (guint_t*)g,
                    (luint_t*)(smraw + hl * 65536 + cc * 8192 + p * 1024),
                    16, 0, 0);
            }
        }
    }
    dmaB(0, 0);
    dmaB(1, 1);
    asm volatile("s_waitcnt vmcnt(0)" ::: "memory");
    __syncthreads();   // A visible to all waves; the ONLY loop-side barrier

    // register fragment double-buffer (all indices static)
    half8_t fah[2][8], fal[2][8], fbh[2][2], fbl[2][2];
    float csq0 = 0.f, csq1 = 0.f;

    // F(0) into set 0 (cc = 0, B buf 0)
    {
        const int ab = lr * 32 + koq * 8;
        #pragma unroll
        for (int mf = 0; mf < 8; ++mf) {
            fah[0][mf] = *(const half8_t*)&smA[ab + mf * 512];
            fal[0][mf] = *(const half8_t*)&smA[32768 + ab + mf * 512];
        }
        const int bb = lr * 32 + koq * 8;
        fbh[0][0] = *(const half8_t*)&smBwh[bb];
        fbh[0][1] = *(const half8_t*)&smBwh[bb + 512];
        fbl[0][0] = *(const half8_t*)&smBwh[bb + 1024];
        fbl[0][1] = *(const half8_t*)&smBwh[bb + 1536];
    }

#define SUBITER(S_, FC, FN, BUFD, BUFR, DO_CSQ, DO_FOLD)                     \
  {                                                                          \
    const int S = (S_);                                                      \
    asm volatile("s_waitcnt vmcnt(0) lgkmcnt(0)" ::: "memory");              \
    if (S + 2 < NSTG) dmaB((BUFD), S + 2);                                   \
    if (DO_CSQ && (S & 7) == 0) {                                            \
      const int jb0 = (S >> 3) * TN + wx * 32 + lr;                          \
      csq0 = cbsq[jb0];                                                      \
      csq1 = cbsq[jb0 + 16];                                                 \
    }                                                                        \
    if (S + 1 < NSTG) {                                                      \
      const int ccn = (S + 1) & 7;                                           \
      const int ab  = ccn * 4096 + lr * 32 + koq * 8;                        \
      _Pragma("unroll")                                                      \
      for (int mf = 0; mf < 8; ++mf) {                                       \
        fah[FN][mf] = *(const half8_t*)&smA[ab + mf * 512];                  \
        fal[FN][mf] = *(const half8_t*)&smA[32768 + ab + mf * 512];          \
      }                                                                      \
      const int bb = (BUFR) * 2048 + lr * 32 + koq * 8;                      \
      fbh[FN][0] = *(const half8_t*)&smBwh[bb];                              \
      fbh[FN][1] = *(const half8_t*)&smBwh[bb + 512];                        \
      fbl[FN][0] = *(const half8_t*)&smBwh[bb + 1024];                       \
      fbl[FN][1] = *(const half8_t*)&smBwh[bb + 1536];                       \
    }                                                                        \
    _Pragma("unroll")                                                        \
    for (int mf = 0; mf < 8; ++mf) {                                         \
      acc[mf][0] = __builtin_amdgcn_mfma_f32_16x16x32_f16(                   \
          fah[FC][mf], fbh[FC][0], acc[mf][0], 0, 0, 0);                     \
      acc[mf][1] = __builtin_amdgcn_mfma_f32_16x16x32_f16(                   \
          fah[FC][mf], fbh[FC][1], acc[mf][1], 0, 0, 0);                     \
    }                                                                        \
    _Pragma("unroll")                                                        \
    for (int mf = 0; mf < 8; ++mf) {                                         \
      acc[mf][0] = __builtin_amdgcn_mfma_f32_16x16x32_f16(                   \
          fah[FC][mf], fbl[FC][0], acc[mf][0], 0, 0, 0);                     \
      acc[mf][1] = __builtin_amdgcn_mfma_f32_16x16x32_f16(                   \
          fah[FC][mf], fbl[FC][1], acc[mf][1], 0, 0, 0);                     \
    }                                                                        \
    _Pragma("unroll")                                                        \
    for (int mf = 0; mf < 8; ++mf) {                                         \
      acc[mf][0] = __builtin_amdgcn_mfma_f32_16x16x32_f16(                   \
          fal[FC][mf], fbh[FC][0], acc[mf][0], 0, 0, 0);                     \
      acc[mf][1] = __builtin_amdgcn_mfma_f32_16x16x32_f16(                   \
          fal[FC][mf], fbh[FC][1], acc[mf][1], 0, 0, 0);                     \
    }                                                                        \
    if (DO_FOLD && (S & 7) == 7) {                                           \
      const int jb7 = (S >> 3) * TN + wx * 32 + lr;                          \
      _Pragma("unroll")                                                      \
      for (int mf = 0; mf < 8; ++mf) {                                       \
        _Pragma("unroll")                                                    \
        for (int r = 0; r < 4; ++r) {                                        \
          const int e = mf * 4 + r;                                          \
          float s0 = csq0 - 2.0f * acc[mf][0][r];                            \
          float s1 = csq1 - 2.0f * acc[mf][1][r];                            \
          float sv = s0; int si = jb7;                                       \
          if (s1 < sv) { sv = s1; si = jb7 + 16; }                           \
          if (sv < minv[e]) { minv[e] = sv; mini[e] = si; }                  \
          acc[mf][0][r] = 0.f;                                               \
          acc[mf][1][r] = 0.f;                                               \
        }                                                                    \
      }                                                                      \
    }                                                                        \
  }

    #pragma unroll 1
    for (int sp = 0; sp < NSTG; sp += 2) {
        SUBITER(sp,     0, 1, 0, 1, 1, 0);
        SUBITER(sp + 1, 1, 0, 1, 0, 0, 1);
    }
#undef SUBITER

    // ---- epilogue: cross-lane argmin (16 cols per koq group), then
    //      cross-wave via LDS (aliases the dead B region, after barrier) ----
    __syncthreads();
    float* cand_v = (float*)(smraw + 131072);           // [4][128]
    int*   cand_i = (int*)(smraw + 131072 + 2048);      // [4][128]

    #pragma unroll
    for (int e = 0; e < 32; ++e) {
        float v = minv[e];
        int   x = mini[e];
        #pragma unroll
        for (int m = 1; m <= 8; m <<= 1) {
            float ov = __shfl_xor(v, m, 64);
            int   ox = __shfl_xor(x, m, 64);
            if (ov < v || (ov == v && ox < x)) { v = ov; x = ox; }
        }
        if (lr == 0) {
            int row = (e >> 2) * 16 + koq * 4 + (e & 3);
            cand_v[wx * TM + row] = v;
            cand_i[wx * TM + row] = x;
        }
    }
    __syncthreads();

    if (t < TM) {
        float v0 = cand_v[t];          int i0 = cand_i[t];
        #pragma unroll
        for (int q = 1; q < 4; ++q) {
            float v1 = cand_v[q * TM + t]; int i1 = cand_i[q * TM + t];
            if (v1 < v0 || (v1 == v0 && i1 < i0)) { v0 = v1; i0 = i1; }
        }
        unsigned sb = __float_as_uint(v0);
        sb = (sb & 0x80000000u) ? ~sb : (sb | 0x80000000u);
        packed[n0 + t] = ((unsigned long long)sb << 32) | (unsigned)i0;
    }
}

// ---------------------------------------------------------------------------
// Kernel 3: gather + straight-through + loss partials + histogram
// ---------------------------------------------------------------------------
__global__ void k_gather(const float* __restrict__ emb,
                         const float* __restrict__ ces,
                         const float* __restrict__ usage,
                         const unsigned long long* __restrict__ packed,
                         float* __restrict__ out_eq,
                         float* __restrict__ codes_f,
                         int* __restrict__ hist,
                         float* __restrict__ partials) {
    int t = threadIdx.x;
    int wave = t >> 6, lane = t & 63;
    int n = blockIdx.x * 4 + wave;
    int k = (int)(packed[n] & 0xFFFFFFFFull);
    float uc = fmaxf(usage[k], 1e-5f);
    int c = lane * 4;

    float4 e = *(const float4*)&emb[(size_t)n * CH + c];
    float4 v = *(const float4*)&ces[(size_t)k * CH + c];
    float ea[4] = {e.x, e.y, e.z, e.w};
    float va[4] = {v.x, v.y, v.z, v.w};
    float eqa[4];
    float p = 0.0f;
    #pragma unroll
    for (int q = 0; q < 4; ++q) {
        float cb = va[q] / uc;
        float eq = ea[q] + (cb - ea[q]);
        eqa[q] = eq;
        float d = eq - ea[q];
        p += d * d;
    }
    *(float4*)&out_eq[(size_t)n * CH + c] =
        (float4){eqa[0], eqa[1], eqa[2], eqa[3]};

    #pragma unroll
    for (int off = 32; off; off >>= 1) p += __shfl_down(p, off);
    __shared__ float ps[4];
    if (lane == 0) {
        ps[wave] = p;
        codes_f[n] = (float)k;
        atomicAdd(&hist[k], 1);
    }
    __syncthreads();
    if (t == 0) partials[blockIdx.x] = ps[0] + ps[1] + ps[2] + ps[3];
}

// ---------------------------------------------------------------------------
// Kernel 4: exclusive prefix sum over hist -> offs, cursor (1 block)
// ---------------------------------------------------------------------------
__global__ void k_scan(const int* __restrict__ hist,
                       int* __restrict__ offs,
                       int* __restrict__ cursor) {
    __shared__ int bs[256];
    int t = threadIdx.x;
    int base = t * 32;
    int loc[32];
    int s = 0;
    #pragma unroll
    for (int i = 0; i < 32; ++i) { loc[i] = s; s += hist[base + i]; }
    int mysum = s;
    bs[t] = s;
    __syncthreads();
    for (int off = 1; off < 256; off <<= 1) {
        int v = (t >= off) ? bs[t - off] : 0;
        __syncthreads();
        bs[t] += v;
        __syncthreads();
    }
    int excl = bs[t] - mysum;
    #pragma unroll
    for (int i = 0; i < 32; ++i) {
        int o = excl + loc[i];
        offs[base + i]   = o;
        cursor[base + i] = o;
    }
}

// ---------------------------------------------------------------------------
// Kernel 5: scatter token ids into code-sorted buckets
// ---------------------------------------------------------------------------
__global__ void k_scatter(const unsigned long long* __restrict__ packed,
                          int* __restrict__ cursor,
                          int* __restrict__ bucket) {
    int n = blockIdx.x * 256 + threadIdx.x;
    int k = (int)(packed[n] & 0xFFFFFFFFull);
    int pos = atomicAdd(&cursor[k], 1);
    bucket[pos] = n;
}

// ---------------------------------------------------------------------------
// Kernel 6: per-code EMA (one BLOCK per code: coalesced 1KB row loads,
// thread t owns channel t, no atomics, no wave-serial latency chain)
// ---------------------------------------------------------------------------
__global__ void k_ema(const float* __restrict__ emb,
                      const float* __restrict__ ces,
                      const float* __restrict__ usage,
                      const int* __restrict__ hist,
                      const int* __restrict__ offs,
                      const int* __restrict__ bucket,
                      float* __restrict__ out_ces,
                      float* __restrict__ out_usage) {
    const float s = 0.01f;
    const float oms = 1.0f - s;
    int k = blockIdx.x, t = threadIdx.x;
    int start = offs[k], cnt = hist[k];
    float sum = 0.0f;
    #pragma unroll 2
    for (int i = 0; i < cnt; ++i) {
        int n = bucket[start + i];            // block-uniform (scalar) load
        sum += emb[(size_t)n * CH + t];       // coalesced row
    }
    out_ces[(size_t)k * CH + t] = oms * ces[(size_t)k * CH + t] + s * sum;
    if (t == 0) out_usage[k] = oms * usage[k] + s * (float)cnt;
}

// ---------------------------------------------------------------------------
// Kernel 7: reduce loss partials, mean over 2^23 elements
// ---------------------------------------------------------------------------
__global__ void k_final(const float* __restrict__ partials,
                        float* __restrict__ out_loss) {
    int t = threadIdx.x;
    float p = 0.0f;
    for (int i = t; i < NT / 4; i += 256) p += partials[i];
    #pragma unroll
    for (int off = 32; off; off >>= 1) p += __shfl_down(p, off);
    __shared__ float ps[4];
    if ((t & 63) == 0) ps[t >> 6] = p;
    __syncthreads();
    if (t == 0)
        out_loss[0] = (ps[0] + ps[1] + ps[2] + ps[3]) * (1.0f / 8388608.0f);
}

extern "C" void kernel_launch(void* const* d_in, const int* in_sizes, int n_in,
                              void* d_out, int out_size, void* d_ws, size_t ws_size,
                              hipStream_t stream) {
    const float* emb   = (const float*)d_in[0];  // [32768, 256]
    const float* usage = (const float*)d_in[1];  // [8192]
    const float* ces   = (const float*)d_in[2];  // [8192, 256]

    float* out      = (float*)d_out;
    float* o_codes  = out;                       // 32768
    float* o_eq     = out + NT;                  // 8388608
    float* o_loss   = o_eq + (size_t)NT * CH;    // 1
    float* o_usage  = o_loss + 1;                // 8192
    float* o_ces    = o_usage + KC;              // 2097152

    unsigned long long* packed = (unsigned long long*)d_ws;   // NT u64
    float* cbsq     = (float*)(packed + NT);                  // KC
    float* partials = cbsq + KC;                              // NT/4
    int* hist   = (int*)(partials + NT / 4);                  // KC
    int* offs   = hist + KC;                                  // KC
    int* cursor = offs + KC;                                  // KC
    int* bucket = cursor + KC;                                // NT
    _Float16* eh  = (_Float16*)(bucket + NT);                 // NT*CH
    _Float16* el  = eh + (size_t)NT * CH;
    _Float16* cbh = el + (size_t)NT * CH;                     // KC*CH
    _Float16* cbl = cbh + (size_t)KC * CH;

    k_prep<<<KC + NT * CH / 1024, 256, 0, stream>>>(
        usage, ces, emb, cbh, cbl, cbsq, eh, el, hist);
    k_argmin<<<NT / TM, 256, 0, stream>>>(eh, el, cbh, cbl, cbsq, packed);
    k_gather<<<NT / 4, 256, 0, stream>>>(emb, ces, usage, packed, o_eq,
                                         o_codes, hist, partials);
    k_scan<<<1, 256, 0, stream>>>(hist, offs, cursor);
    k_scatter<<<NT / 256, 256, 0, stream>>>(packed, cursor, bucket);
    k_ema<<<KC, 256, 0, stream>>>(emb, ces, usage, hist, offs, bucket,
                                  o_ces, o_usage);
    k_final<<<1, 256, 0, stream>>>(partials, o_loss);
}